// Round 4
// baseline (187.542 us; speedup 1.0000x reference)
//
#include <hip/hip_runtime.h>

#define NNODES 50000
#define NEDGES 640000
#define NF 128
#define NB 196            // scan blocks: 196*256 = 50176 >= NNODES

typedef __attribute__((ext_vector_type(8))) short bf16x8;
typedef __attribute__((ext_vector_type(4))) float f32x4;

__device__ inline unsigned short f2bf(float f) {
  unsigned u = __float_as_uint(f);
  u += 0x7fffu + ((u >> 16) & 1u);   // round-to-nearest-even
  return (unsigned short)(u >> 16);
}
__device__ inline float bf2f(unsigned short s) {
  return __uint_as_float((unsigned)s << 16);
}

// ---------------- K: zero degree counters + BN stats ----------------
__global__ __launch_bounds__(256) void k_zero(int* __restrict__ deg,
                                              float* __restrict__ stats) {
  int i = blockIdx.x * 256 + threadIdx.x;
  if (i < NB * 256) deg[i] = 0;
  if (blockIdx.x == 0) stats[threadIdx.x] = 0.f;
}

// ---------------- K: W -> fragment-ordered bf16 hi/lo (both W1, W2) ----------------
// frag index f = (((ks*8+cf)*64)+lane)*8 + j ;  k = ks*32+(lane>>4)*8+j ; n = cf*16+(lane&15)
__global__ __launch_bounds__(256) void k_wprep(const float* __restrict__ W1,
                                               const float* __restrict__ W2,
                                               unsigned short* __restrict__ wp) {
  int i = blockIdx.x * 256 + threadIdx.x;   // 0..32767
  int which = i >> 14;
  int f = i & 16383;
  int j = f & 7, lane = (f >> 3) & 63, cf = (f >> 9) & 7, ks = f >> 12;
  int k = ks * 32 + ((lane >> 4) << 3) + j;
  int n = cf * 16 + (lane & 15);
  float w = (which ? W2 : W1)[k * NF + n];
  unsigned short hi = f2bf(w);
  unsigned short lo = f2bf(w - bf2f(hi));
  unsigned short* dst = wp + which * 32768;
  dst[f] = hi;
  dst[16384 + f] = lo;
}

// ---------------- K: histogram of dst ----------------
__global__ __launch_bounds__(256) void k_hist(const int* __restrict__ ei,
                                              int* __restrict__ deg) {
  int e = blockIdx.x * 256 + threadIdx.x;
  atomicAdd(&deg[ei[NEDGES + e]], 1);
}

// ---------------- scan stages ----------------
__global__ __launch_bounds__(256) void k_scan1(const int* __restrict__ deg,
                                               int* __restrict__ bsum) {
  __shared__ int s[256];
  int t = threadIdx.x;
  s[t] = deg[blockIdx.x * 256 + t];
  __syncthreads();
  for (int d = 128; d > 0; d >>= 1) {
    if (t < d) s[t] += s[t + d];
    __syncthreads();
  }
  if (t == 0) bsum[blockIdx.x] = s[0];
}

__global__ __launch_bounds__(256) void k_scan2(const int* __restrict__ bsum,
                                               int* __restrict__ boff) {
  __shared__ int s[256];
  int t = threadIdx.x;
  int v = (t < NB) ? bsum[t] : 0;
  s[t] = v;
  __syncthreads();
  for (int d = 1; d < 256; d <<= 1) {
    int u = (t >= d) ? s[t - d] : 0;
    __syncthreads();
    s[t] += u;
    __syncthreads();
  }
  if (t < NB) boff[t] = s[t] - v;
}

__global__ __launch_bounds__(256) void k_scan3(const int* __restrict__ deg,
                                               const int* __restrict__ boff,
                                               int* __restrict__ off,
                                               int* __restrict__ cursor) {
  __shared__ int s[256];
  int t = threadIdx.x;
  int i = blockIdx.x * 256 + t;
  int v = deg[i];
  s[t] = v;
  __syncthreads();
  for (int d = 1; d < 256; d <<= 1) {
    int u = (t >= d) ? s[t - d] : 0;
    __syncthreads();
    s[t] += u;
    __syncthreads();
  }
  int excl = boff[blockIdx.x] + s[t] - v;
  if (i < NNODES) {
    off[i] = excl;
    cursor[i] = excl;
  }
  if (i == 0) off[NNODES] = NEDGES;
}

// ---------------- K: reorder — slot[pos] = src, bucketed by dst ----------------
__global__ __launch_bounds__(256) void k_reorder(const int* __restrict__ ei,
                                                 int* __restrict__ cursor,
                                                 int* __restrict__ slot) {
  int e = blockIdx.x * 256 + threadIdx.x;
  int d = ei[NEDGES + e];
  int pos = atomicAdd(&cursor[d], 1);
  slot[pos] = ei[e];
}

// ---------------- K: gather-sum, column-tiled for L2 locality ----------------
// grid (nodeblocks, 4 tiles); wave per node per tile; lane = edge(e=l>>3) x colquad(c=l&7)
__global__ __launch_bounds__(256) void k_gather(const float* __restrict__ x,
                                                const int* __restrict__ off,
                                                const int* __restrict__ slot,
                                                float* __restrict__ h) {
  const int t = threadIdx.x;
  const int wv = t >> 6, l = t & 63;
  const int node = blockIdx.x * 4 + wv;
  if (node >= NNODES) return;
  const int col = (blockIdx.y << 5) + ((l & 7) << 2);
  const int e = l >> 3;
  const int beg = off[node], end = off[node + 1];
  float4 a = make_float4(0.f, 0.f, 0.f, 0.f);
  float4 b = make_float4(0.f, 0.f, 0.f, 0.f);
  int j = beg + e;
  for (; j + 8 < end; j += 16) {
    int s0 = slot[j], s1 = slot[j + 8];
    float4 v0 = *(const float4*)(x + (size_t)s0 * NF + col);
    float4 v1 = *(const float4*)(x + (size_t)s1 * NF + col);
    a.x += v0.x; a.y += v0.y; a.z += v0.z; a.w += v0.w;
    b.x += v1.x; b.y += v1.y; b.z += v1.z; b.w += v1.w;
  }
  if (j < end) {
    int s0 = slot[j];
    float4 v0 = *(const float4*)(x + (size_t)s0 * NF + col);
    a.x += v0.x; a.y += v0.y; a.z += v0.z; a.w += v0.w;
  }
  a.x += b.x; a.y += b.y; a.z += b.z; a.w += b.w;
#pragma unroll
  for (int d = 8; d < 64; d <<= 1) {
    a.x += __shfl_xor(a.x, d);
    a.y += __shfl_xor(a.y, d);
    a.z += __shfl_xor(a.z, d);
    a.w += __shfl_xor(a.w, d);
  }
  if (e == 0) {
    const float4 sv = *(const float4*)(x + (size_t)node * NF + col);
    a.x += sv.x; a.y += sv.y; a.z += sv.z; a.w += sv.w;
    *(float4*)(h + (size_t)node * NF + col) = a;
  }
}

// ---------------- MFMA GEMM: out = A(50000x128) @ W(128x128) + bias ----------------
// bf16x3 fp32-emulation. BM=128/block (each wave: 2 row-fragments, rows +0 and +64).
// MODE 0: relu, in-place, BN sum/sumsq.  MODE 1: BN affine on A, +b2, write out.
template <int MODE>
__global__ __launch_bounds__(256, 2) void k_gemm(const float* __restrict__ A,
                                                 const unsigned short* __restrict__ wprep,
                                                 const float* __restrict__ bias,
                                                 const float* __restrict__ scsh,
                                                 float* __restrict__ stats,
                                                 float* __restrict__ out) {
  __shared__ unsigned short wl[32768];   // 64 KB: hi[16384] then lo[16384]
  __shared__ float red[2][4][128];       // 4 KB: BN cross-wave reduce

  const int t = threadIdx.x;
  const int wv = t >> 6;
  const int l = t & 63;
  const int wrow0 = blockIdx.x * 128 + wv * 16;

  // ---- A fragments: row = wrow0 + m*64 + (l&15); k = ks*32 + (l>>4)*8 + j
  float4 areg[2][8];
#pragma unroll
  for (int m = 0; m < 2; ++m) {
    const int arow = wrow0 + m * 64 + (l & 15);
    const bool okA = arow < NNODES;
#pragma unroll
    for (int ks = 0; ks < 4; ++ks) {
      if (okA) {
        const float* p = A + (size_t)arow * NF + ks * 32 + ((l >> 4) << 3);
        areg[m][2 * ks]     = *(const float4*)(p);
        areg[m][2 * ks + 1] = *(const float4*)(p + 4);
      } else {
        areg[m][2 * ks] = areg[m][2 * ks + 1] = make_float4(0.f, 0.f, 0.f, 0.f);
      }
    }
  }

  // ---- stage frag-ordered W (64 KB) ----
  const float4* src = (const float4*)wprep;
#pragma unroll
  for (int it = 0; it < 16; ++it) {
    ((float4*)wl)[it * 256 + t] = src[it * 256 + t];
  }
  __syncthreads();

  // ---- compute ----
  f32x4 acc[2][8];
#pragma unroll
  for (int m = 0; m < 2; ++m)
#pragma unroll
    for (int cf = 0; cf < 8; ++cf) acc[m][cf] = (f32x4){0.f, 0.f, 0.f, 0.f};

#pragma unroll
  for (int ks = 0; ks < 4; ++ks) {
    float4 sc0, sc1, sh0, sh1;
    if (MODE == 1) {
      const float* scp = scsh + ks * 32 + ((l >> 4) << 3);
      sc0 = *(const float4*)(scp);
      sc1 = *(const float4*)(scp + 4);
      sh0 = *(const float4*)(scp + 128);
      sh1 = *(const float4*)(scp + 132);
    }
    bf16x8 ah[2], al[2];
#pragma unroll
    for (int m = 0; m < 2; ++m) {
      float av[8];
      float4 a0 = areg[m][2 * ks], a1 = areg[m][2 * ks + 1];
      av[0] = a0.x; av[1] = a0.y; av[2] = a0.z; av[3] = a0.w;
      av[4] = a1.x; av[5] = a1.y; av[6] = a1.z; av[7] = a1.w;
      if (MODE == 1) {
        av[0] = fmaf(av[0], sc0.x, sh0.x); av[1] = fmaf(av[1], sc0.y, sh0.y);
        av[2] = fmaf(av[2], sc0.z, sh0.z); av[3] = fmaf(av[3], sc0.w, sh0.w);
        av[4] = fmaf(av[4], sc1.x, sh1.x); av[5] = fmaf(av[5], sc1.y, sh1.y);
        av[6] = fmaf(av[6], sc1.z, sh1.z); av[7] = fmaf(av[7], sc1.w, sh1.w);
      }
#pragma unroll
      for (int j = 0; j < 8; ++j) {
        unsigned short hi = f2bf(av[j]);
        ah[m][j] = (short)hi;
        al[m][j] = (short)f2bf(av[j] - bf2f(hi));
      }
    }
#pragma unroll
    for (int cf = 0; cf < 8; ++cf) {
      const int fo = (((ks * 8 + cf) << 6) + l) << 3;   // ushort offset
      bf16x8 bh  = *(const bf16x8*)(wl + fo);
      bf16x8 bl2 = *(const bf16x8*)(wl + 16384 + fo);
#pragma unroll
      for (int m = 0; m < 2; ++m) {
        acc[m][cf] = __builtin_amdgcn_mfma_f32_16x16x32_bf16(ah[m], bh,  acc[m][cf], 0, 0, 0);
        acc[m][cf] = __builtin_amdgcn_mfma_f32_16x16x32_bf16(al[m], bh,  acc[m][cf], 0, 0, 0);
        acc[m][cf] = __builtin_amdgcn_mfma_f32_16x16x32_bf16(ah[m], bl2, acc[m][cf], 0, 0, 0);
      }
    }
  }

  // ---- epilogue: D layout col = cf*16+(l&15), row = wrow0 + m*64 + (l>>4)*4 + r ----
  const int col16 = l & 15;
  const int rg = l >> 4;
  float bl_[8];
#pragma unroll
  for (int cf = 0; cf < 8; ++cf) bl_[cf] = bias[cf * 16 + col16];

  if (MODE == 0) {
    float cs[8], cq[8];
#pragma unroll
    for (int cf = 0; cf < 8; ++cf) { cs[cf] = 0.f; cq[cf] = 0.f; }
#pragma unroll
    for (int m = 0; m < 2; ++m)
#pragma unroll
      for (int cf = 0; cf < 8; ++cf) {
#pragma unroll
        for (int r = 0; r < 4; ++r) {
          int row = wrow0 + m * 64 + rg * 4 + r;
          if (row < NNODES) {
            float v = fmaxf(acc[m][cf][r] + bl_[cf], 0.f);
            out[(size_t)row * NF + cf * 16 + col16] = v;
            cs[cf] += v;
            cq[cf] += v * v;
          }
        }
      }
#pragma unroll
    for (int cf = 0; cf < 8; ++cf) {
      cs[cf] += __shfl_xor(cs[cf], 16); cs[cf] += __shfl_xor(cs[cf], 32);
      cq[cf] += __shfl_xor(cq[cf], 16); cq[cf] += __shfl_xor(cq[cf], 32);
    }
    if (l < 16) {
#pragma unroll
      for (int cf = 0; cf < 8; ++cf) {
        red[0][wv][cf * 16 + l] = cs[cf];
        red[1][wv][cf * 16 + l] = cq[cf];
      }
    }
    __syncthreads();
    if (t < 128) {
      float s = red[0][0][t] + red[0][1][t] + red[0][2][t] + red[0][3][t];
      float q = red[1][0][t] + red[1][1][t] + red[1][2][t] + red[1][3][t];
      unsafeAtomicAdd(stats + t, s);
      unsafeAtomicAdd(stats + 128 + t, q);
    }
  } else {
#pragma unroll
    for (int m = 0; m < 2; ++m)
#pragma unroll
      for (int cf = 0; cf < 8; ++cf) {
#pragma unroll
        for (int r = 0; r < 4; ++r) {
          int row = wrow0 + m * 64 + rg * 4 + r;
          if (row < NNODES)
            out[(size_t)row * NF + cf * 16 + col16] = acc[m][cf][r] + bl_[cf];
        }
      }
  }
}

// ---------------- K: BN scale/shift finalize ----------------
__global__ __launch_bounds__(128) void k_bnfin(const float* __restrict__ stats,
                                               const float* __restrict__ gamma,
                                               const float* __restrict__ beta,
                                               float* __restrict__ scsh) {
  int c = threadIdx.x;
  const float inv = 1.0f / (float)NNODES;
  float mean = stats[c] * inv;
  float var = stats[128 + c] * inv - mean * mean;
  var = fmaxf(var, 0.f);
  float sc = gamma[c] * rsqrtf(var + 1e-5f);
  scsh[c] = sc;
  scsh[128 + c] = beta[c] - mean * sc;
}

extern "C" void kernel_launch(void* const* d_in, const int* in_sizes, int n_in,
                              void* d_out, int out_size, void* d_ws, size_t ws_size,
                              hipStream_t stream) {
  const float* x     = (const float*)d_in[0];
  const int*   ei    = (const int*)d_in[1];
  const float* W1    = (const float*)d_in[2];
  const float* b1    = (const float*)d_in[3];
  const float* gamma = (const float*)d_in[4];
  const float* beta  = (const float*)d_in[5];
  const float* W2    = (const float*)d_in[6];
  const float* b2    = (const float*)d_in[7];
  float* out = (float*)d_out;
  float* h = (float*)d_out;   // h lives in d_out (rows rewritten in place per block)

  float*          stats = (float*)d_ws;                        // 512 floats
  unsigned short* wp    = (unsigned short*)(stats + 512);      // 65536 ushorts (128 KB)
  int*            deg   = (int*)(wp + 65536);                  // [NB*256]
  int*            off   = deg + NB * 256;                      // [NNODES+1]+pad
  int*            cursor= off + NNODES + 4;                    // [NNODES]
  int*            bsum  = cursor + NNODES;                     // [256]
  int*            boff  = bsum + 256;                          // [256]
  int*            slot  = boff + 256;                          // [NEDGES]

  k_wprep  <<<128, 256, 0, stream>>>(W1, W2, wp);
  k_zero   <<<NB, 256, 0, stream>>>(deg, stats);
  k_hist   <<<NEDGES / 256, 256, 0, stream>>>(ei, deg);
  k_scan1  <<<NB, 256, 0, stream>>>(deg, bsum);
  k_scan2  <<<1, 256, 0, stream>>>(bsum, boff);
  k_scan3  <<<NB, 256, 0, stream>>>(deg, boff, off, cursor);
  k_reorder<<<NEDGES / 256, 256, 0, stream>>>(ei, cursor, slot);
  {
    dim3 g((NNODES + 3) / 4, 4);
    k_gather<<<g, 256, 0, stream>>>(x, off, slot, h);
  }
  k_gemm<0><<<(NNODES + 127) / 128, 256, 0, stream>>>(h, wp, b1, nullptr, stats, h);
  k_bnfin  <<<1, 128, 0, stream>>>(stats, gamma, beta, stats + 256);
  k_gemm<1><<<(NNODES + 127) / 128, 256, 0, stream>>>(h, wp + 32768, b2, stats + 256, nullptr, out);
}

// Round 5
// 160.664 us; speedup vs baseline: 1.1673x; 1.1673x over previous
//
#include <hip/hip_runtime.h>
#include <hip/hip_fp16.h>

#define NNODES 50000
#define NEDGES 640000
#define NF 128
#define NB 196            // scan blocks: 196*256 = 50176 >= NNODES

typedef __attribute__((ext_vector_type(8))) short bf16x8;
typedef __attribute__((ext_vector_type(4))) float f32x4;

__device__ inline unsigned short f2bf(float f) {
  unsigned u = __float_as_uint(f);
  u += 0x7fffu + ((u >> 16) & 1u);   // round-to-nearest-even
  return (unsigned short)(u >> 16);
}
__device__ inline float bf2f(unsigned short s) {
  return __uint_as_float((unsigned)s << 16);
}

// ---------------- K: x -> fp16 table; also zero deg + stats ----------------
__global__ __launch_bounds__(256) void k_xh(const float* __restrict__ x,
                                            unsigned short* __restrict__ xh,
                                            int* __restrict__ deg,
                                            float* __restrict__ stats) {
  int i = blockIdx.x * 256 + threadIdx.x;   // i indexes 8-float chunks
  if (i < NNODES * NF / 8) {
    const float4 a = ((const float4*)x)[2 * i];
    const float4 b = ((const float4*)x)[2 * i + 1];
    __half2 h0 = __float22half2_rn(make_float2(a.x, a.y));
    __half2 h1 = __float22half2_rn(make_float2(a.z, a.w));
    __half2 h2 = __float22half2_rn(make_float2(b.x, b.y));
    __half2 h3 = __float22half2_rn(make_float2(b.z, b.w));
    uint4 v;
    v.x = *(unsigned*)&h0; v.y = *(unsigned*)&h1;
    v.z = *(unsigned*)&h2; v.w = *(unsigned*)&h3;
    ((uint4*)xh)[i] = v;
  }
  if (blockIdx.x < NB) deg[blockIdx.x * 256 + threadIdx.x] = 0;
  if (blockIdx.x == 0 && threadIdx.x < 512) stats[threadIdx.x] = 0.f;
}

// ---------------- K: zero (fallback path only) ----------------
__global__ __launch_bounds__(256) void k_zero(int* __restrict__ deg,
                                              float* __restrict__ stats) {
  int i = blockIdx.x * 256 + threadIdx.x;
  if (i < NB * 256) deg[i] = 0;
  if (blockIdx.x == 0) stats[threadIdx.x] = 0.f;
}

// ---------------- K: W -> fragment-ordered bf16 hi/lo (both W1, W2) ----------------
__global__ __launch_bounds__(256) void k_wprep(const float* __restrict__ W1,
                                               const float* __restrict__ W2,
                                               unsigned short* __restrict__ wp) {
  int i = blockIdx.x * 256 + threadIdx.x;   // 0..32767
  int which = i >> 14;
  int f = i & 16383;
  int j = f & 7, lane = (f >> 3) & 63, cf = (f >> 9) & 7, ks = f >> 12;
  int k = ks * 32 + ((lane >> 4) << 3) + j;
  int n = cf * 16 + (lane & 15);
  float w = (which ? W2 : W1)[k * NF + n];
  unsigned short hi = f2bf(w);
  unsigned short lo = f2bf(w - bf2f(hi));
  unsigned short* dst = wp + which * 32768;
  dst[f] = hi;
  dst[16384 + f] = lo;
}

// ---------------- K: histogram of dst ----------------
__global__ __launch_bounds__(256) void k_hist(const int* __restrict__ ei,
                                              int* __restrict__ deg) {
  int e = blockIdx.x * 256 + threadIdx.x;
  atomicAdd(&deg[ei[NEDGES + e]], 1);
}

// ---------------- scan stages ----------------
__global__ __launch_bounds__(256) void k_scan1(const int* __restrict__ deg,
                                               int* __restrict__ bsum) {
  __shared__ int s[256];
  int t = threadIdx.x;
  s[t] = deg[blockIdx.x * 256 + t];
  __syncthreads();
  for (int d = 128; d > 0; d >>= 1) {
    if (t < d) s[t] += s[t + d];
    __syncthreads();
  }
  if (t == 0) bsum[blockIdx.x] = s[0];
}

__global__ __launch_bounds__(256) void k_scan2(const int* __restrict__ bsum,
                                               int* __restrict__ boff) {
  __shared__ int s[256];
  int t = threadIdx.x;
  int v = (t < NB) ? bsum[t] : 0;
  s[t] = v;
  __syncthreads();
  for (int d = 1; d < 256; d <<= 1) {
    int u = (t >= d) ? s[t - d] : 0;
    __syncthreads();
    s[t] += u;
    __syncthreads();
  }
  if (t < NB) boff[t] = s[t] - v;
}

__global__ __launch_bounds__(256) void k_scan3(const int* __restrict__ deg,
                                               const int* __restrict__ boff,
                                               int* __restrict__ off,
                                               int* __restrict__ cursor) {
  __shared__ int s[256];
  int t = threadIdx.x;
  int i = blockIdx.x * 256 + t;
  int v = deg[i];
  s[t] = v;
  __syncthreads();
  for (int d = 1; d < 256; d <<= 1) {
    int u = (t >= d) ? s[t - d] : 0;
    __syncthreads();
    s[t] += u;
    __syncthreads();
  }
  int excl = boff[blockIdx.x] + s[t] - v;
  if (i < NNODES) {
    off[i] = excl;
    cursor[i] = excl;
  }
  if (i == 0) off[NNODES] = NEDGES;
}

// ---------------- K: reorder — slot[pos] = src, bucketed by dst ----------------
__global__ __launch_bounds__(256) void k_reorder(const int* __restrict__ ei,
                                                 int* __restrict__ cursor,
                                                 int* __restrict__ slot) {
  int e = blockIdx.x * 256 + threadIdx.x;
  int d = ei[NEDGES + e];
  int pos = atomicAdd(&cursor[d], 1);
  slot[pos] = ei[e];
}

// ---------------- K: gather-sum from fp16 table, wave per node ----------------
// lane: e = l>>4 (4 edges/iter), cols = (l&15)*8 halves (16B). unroll x2 -> 8 edges in flight.
__device__ inline void add8h(float* a, uint4 v) {
  const __half2* p = (const __half2*)&v;
#pragma unroll
  for (int q = 0; q < 4; ++q) {
    float2 f = __half22float2(p[q]);
    a[2 * q] += f.x;
    a[2 * q + 1] += f.y;
  }
}

__global__ __launch_bounds__(256) void k_gather_h(const float* __restrict__ x,
                                                  const unsigned short* __restrict__ xh,
                                                  const int* __restrict__ off,
                                                  const int* __restrict__ slot,
                                                  float* __restrict__ h) {
  const int t = threadIdx.x;
  const int wv = t >> 6, l = t & 63;
  const int node = blockIdx.x * 4 + wv;
  if (node >= NNODES) return;
  const int cg = (l & 15) << 3;    // half-index base
  const int e = l >> 4;            // 0..3
  const int beg = off[node], end = off[node + 1];
  float a[8] = {0.f, 0.f, 0.f, 0.f, 0.f, 0.f, 0.f, 0.f};
  float b[8] = {0.f, 0.f, 0.f, 0.f, 0.f, 0.f, 0.f, 0.f};
  int j = beg + e;
  for (; j + 4 < end; j += 8) {
    const uint4 v0 = *(const uint4*)(xh + (size_t)slot[j] * NF + cg);
    const uint4 v1 = *(const uint4*)(xh + (size_t)slot[j + 4] * NF + cg);
    add8h(a, v0);
    add8h(b, v1);
  }
  if (j < end) {
    const uint4 v0 = *(const uint4*)(xh + (size_t)slot[j] * NF + cg);
    add8h(a, v0);
  }
#pragma unroll
  for (int q = 0; q < 8; ++q) a[q] += b[q];
#pragma unroll
  for (int q = 0; q < 8; ++q) {
    a[q] += __shfl_xor(a[q], 16);
    a[q] += __shfl_xor(a[q], 32);
  }
  if (e == 0) {
    const float4 s0 = *(const float4*)(x + (size_t)node * NF + cg);
    const float4 s1 = *(const float4*)(x + (size_t)node * NF + cg + 4);
    a[0] += s0.x; a[1] += s0.y; a[2] += s0.z; a[3] += s0.w;
    a[4] += s1.x; a[5] += s1.y; a[6] += s1.z; a[7] += s1.w;
    *(float4*)(h + (size_t)node * NF + cg) = make_float4(a[0], a[1], a[2], a[3]);
    *(float4*)(h + (size_t)node * NF + cg + 4) = make_float4(a[4], a[5], a[6], a[7]);
  }
}

// ---------------- K: gather-sum fp32 (fallback if ws too small) ----------------
__global__ __launch_bounds__(256) void k_gather_f(const float* __restrict__ x,
                                                  const int* __restrict__ off,
                                                  const int* __restrict__ slot,
                                                  float* __restrict__ h) {
  int t = threadIdx.x;
  int l = t & 63;
  int node = blockIdx.x * 4 + (t >> 6);
  if (node >= NNODES) return;
  int c = (l & 31) << 2;
  int half = l >> 5;
  int beg = off[node], end = off[node + 1];
  float4 a = make_float4(0.f, 0.f, 0.f, 0.f);
  float4 b = make_float4(0.f, 0.f, 0.f, 0.f);
  int j = beg + half;
  for (; j + 2 < end; j += 4) {
    int s0 = slot[j], s1 = slot[j + 2];
    float4 v0 = *(const float4*)(x + (size_t)s0 * NF + c);
    float4 v1 = *(const float4*)(x + (size_t)s1 * NF + c);
    a.x += v0.x; a.y += v0.y; a.z += v0.z; a.w += v0.w;
    b.x += v1.x; b.y += v1.y; b.z += v1.z; b.w += v1.w;
  }
  if (j < end) {
    int s0 = slot[j];
    float4 v0 = *(const float4*)(x + (size_t)s0 * NF + c);
    a.x += v0.x; a.y += v0.y; a.z += v0.z; a.w += v0.w;
  }
  a.x += b.x; a.y += b.y; a.z += b.z; a.w += b.w;
  a.x += __shfl_xor(a.x, 32);
  a.y += __shfl_xor(a.y, 32);
  a.z += __shfl_xor(a.z, 32);
  a.w += __shfl_xor(a.w, 32);
  if (half == 0) {
    const float4 sv = *(const float4*)(x + (size_t)node * NF + c);
    a.x += sv.x; a.y += sv.y; a.z += sv.z; a.w += sv.w;
    *(float4*)(h + (size_t)node * NF + c) = a;
  }
}

// ---------------- MFMA GEMM (unchanged from R4): BM=128, bf16x3 emulation ----------------
template <int MODE>
__global__ __launch_bounds__(256, 2) void k_gemm(const float* __restrict__ A,
                                                 const unsigned short* __restrict__ wprep,
                                                 const float* __restrict__ bias,
                                                 const float* __restrict__ scsh,
                                                 float* __restrict__ stats,
                                                 float* __restrict__ out) {
  __shared__ unsigned short wl[32768];   // 64 KB: hi[16384] then lo[16384]
  __shared__ float red[2][4][128];       // 4 KB: BN cross-wave reduce

  const int t = threadIdx.x;
  const int wv = t >> 6;
  const int l = t & 63;
  const int wrow0 = blockIdx.x * 128 + wv * 16;

  float4 areg[2][8];
#pragma unroll
  for (int m = 0; m < 2; ++m) {
    const int arow = wrow0 + m * 64 + (l & 15);
    const bool okA = arow < NNODES;
#pragma unroll
    for (int ks = 0; ks < 4; ++ks) {
      if (okA) {
        const float* p = A + (size_t)arow * NF + ks * 32 + ((l >> 4) << 3);
        areg[m][2 * ks]     = *(const float4*)(p);
        areg[m][2 * ks + 1] = *(const float4*)(p + 4);
      } else {
        areg[m][2 * ks] = areg[m][2 * ks + 1] = make_float4(0.f, 0.f, 0.f, 0.f);
      }
    }
  }

  const float4* src = (const float4*)wprep;
#pragma unroll
  for (int it = 0; it < 16; ++it) {
    ((float4*)wl)[it * 256 + t] = src[it * 256 + t];
  }
  __syncthreads();

  f32x4 acc[2][8];
#pragma unroll
  for (int m = 0; m < 2; ++m)
#pragma unroll
    for (int cf = 0; cf < 8; ++cf) acc[m][cf] = (f32x4){0.f, 0.f, 0.f, 0.f};

#pragma unroll
  for (int ks = 0; ks < 4; ++ks) {
    float4 sc0, sc1, sh0, sh1;
    if (MODE == 1) {
      const float* scp = scsh + ks * 32 + ((l >> 4) << 3);
      sc0 = *(const float4*)(scp);
      sc1 = *(const float4*)(scp + 4);
      sh0 = *(const float4*)(scp + 128);
      sh1 = *(const float4*)(scp + 132);
    }
    bf16x8 ah[2], al[2];
#pragma unroll
    for (int m = 0; m < 2; ++m) {
      float av[8];
      float4 a0 = areg[m][2 * ks], a1 = areg[m][2 * ks + 1];
      av[0] = a0.x; av[1] = a0.y; av[2] = a0.z; av[3] = a0.w;
      av[4] = a1.x; av[5] = a1.y; av[6] = a1.z; av[7] = a1.w;
      if (MODE == 1) {
        av[0] = fmaf(av[0], sc0.x, sh0.x); av[1] = fmaf(av[1], sc0.y, sh0.y);
        av[2] = fmaf(av[2], sc0.z, sh0.z); av[3] = fmaf(av[3], sc0.w, sh0.w);
        av[4] = fmaf(av[4], sc1.x, sh1.x); av[5] = fmaf(av[5], sc1.y, sh1.y);
        av[6] = fmaf(av[6], sc1.z, sh1.z); av[7] = fmaf(av[7], sc1.w, sh1.w);
      }
#pragma unroll
      for (int j = 0; j < 8; ++j) {
        unsigned short hi = f2bf(av[j]);
        ah[m][j] = (short)hi;
        al[m][j] = (short)f2bf(av[j] - bf2f(hi));
      }
    }
#pragma unroll
    for (int cf = 0; cf < 8; ++cf) {
      const int fo = (((ks * 8 + cf) << 6) + l) << 3;   // ushort offset
      bf16x8 bh  = *(const bf16x8*)(wl + fo);
      bf16x8 bl2 = *(const bf16x8*)(wl + 16384 + fo);
#pragma unroll
      for (int m = 0; m < 2; ++m) {
        acc[m][cf] = __builtin_amdgcn_mfma_f32_16x16x32_bf16(ah[m], bh,  acc[m][cf], 0, 0, 0);
        acc[m][cf] = __builtin_amdgcn_mfma_f32_16x16x32_bf16(al[m], bh,  acc[m][cf], 0, 0, 0);
        acc[m][cf] = __builtin_amdgcn_mfma_f32_16x16x32_bf16(ah[m], bl2, acc[m][cf], 0, 0, 0);
      }
    }
  }

  const int col16 = l & 15;
  const int rg = l >> 4;
  float bl_[8];
#pragma unroll
  for (int cf = 0; cf < 8; ++cf) bl_[cf] = bias[cf * 16 + col16];

  if (MODE == 0) {
    float cs[8], cq[8];
#pragma unroll
    for (int cf = 0; cf < 8; ++cf) { cs[cf] = 0.f; cq[cf] = 0.f; }
#pragma unroll
    for (int m = 0; m < 2; ++m)
#pragma unroll
      for (int cf = 0; cf < 8; ++cf) {
#pragma unroll
        for (int r = 0; r < 4; ++r) {
          int row = wrow0 + m * 64 + rg * 4 + r;
          if (row < NNODES) {
            float v = fmaxf(acc[m][cf][r] + bl_[cf], 0.f);
            out[(size_t)row * NF + cf * 16 + col16] = v;
            cs[cf] += v;
            cq[cf] += v * v;
          }
        }
      }
#pragma unroll
    for (int cf = 0; cf < 8; ++cf) {
      cs[cf] += __shfl_xor(cs[cf], 16); cs[cf] += __shfl_xor(cs[cf], 32);
      cq[cf] += __shfl_xor(cq[cf], 16); cq[cf] += __shfl_xor(cq[cf], 32);
    }
    if (l < 16) {
#pragma unroll
      for (int cf = 0; cf < 8; ++cf) {
        red[0][wv][cf * 16 + l] = cs[cf];
        red[1][wv][cf * 16 + l] = cq[cf];
      }
    }
    __syncthreads();
    if (t < 128) {
      float s = red[0][0][t] + red[0][1][t] + red[0][2][t] + red[0][3][t];
      float q = red[1][0][t] + red[1][1][t] + red[1][2][t] + red[1][3][t];
      unsafeAtomicAdd(stats + t, s);
      unsafeAtomicAdd(stats + 128 + t, q);
    }
  } else {
#pragma unroll
    for (int m = 0; m < 2; ++m)
#pragma unroll
      for (int cf = 0; cf < 8; ++cf) {
#pragma unroll
        for (int r = 0; r < 4; ++r) {
          int row = wrow0 + m * 64 + rg * 4 + r;
          if (row < NNODES)
            out[(size_t)row * NF + cf * 16 + col16] = acc[m][cf][r] + bl_[cf];
        }
      }
  }
}

// ---------------- K: BN scale/shift finalize ----------------
__global__ __launch_bounds__(128) void k_bnfin(const float* __restrict__ stats,
                                               const float* __restrict__ gamma,
                                               const float* __restrict__ beta,
                                               float* __restrict__ scsh) {
  int c = threadIdx.x;
  const float inv = 1.0f / (float)NNODES;
  float mean = stats[c] * inv;
  float var = stats[128 + c] * inv - mean * mean;
  var = fmaxf(var, 0.f);
  float sc = gamma[c] * rsqrtf(var + 1e-5f);
  scsh[c] = sc;
  scsh[128 + c] = beta[c] - mean * sc;
}

extern "C" void kernel_launch(void* const* d_in, const int* in_sizes, int n_in,
                              void* d_out, int out_size, void* d_ws, size_t ws_size,
                              hipStream_t stream) {
  const float* x     = (const float*)d_in[0];
  const int*   ei    = (const int*)d_in[1];
  const float* W1    = (const float*)d_in[2];
  const float* b1    = (const float*)d_in[3];
  const float* gamma = (const float*)d_in[4];
  const float* beta  = (const float*)d_in[5];
  const float* W2    = (const float*)d_in[6];
  const float* b2    = (const float*)d_in[7];
  float* out = (float*)d_out;
  float* h = (float*)d_out;   // h lives in d_out (rows rewritten in place per block)

  float*          stats = (float*)d_ws;                        // 512 floats
  unsigned short* wp    = (unsigned short*)(stats + 512);      // 65536 ushorts (128 KB)
  int*            deg   = (int*)(wp + 65536);                  // [NB*256]
  int*            off   = deg + NB * 256;                      // [NNODES+1]+pad
  int*            cursor= off + NNODES + 4;                    // [NNODES]
  int*            bsum  = cursor + NNODES;                     // [256]
  int*            boff  = bsum + 256;                          // [256]
  int*            slot  = boff + 256;                          // [NEDGES]
  unsigned short* xh    = (unsigned short*)(slot + NEDGES);    // [NNODES*NF] fp16 (12.8 MB)

  const size_t need = (size_t)((char*)(xh + (size_t)NNODES * NF) - (char*)d_ws);
  const bool use_h = ws_size >= need;

  k_wprep<<<128, 256, 0, stream>>>(W1, W2, wp);
  if (use_h) {
    k_xh<<<(NNODES * NF / 8 + 255) / 256, 256, 0, stream>>>(x, xh, deg, stats);
  } else {
    k_zero<<<NB, 256, 0, stream>>>(deg, stats);
  }
  k_hist   <<<NEDGES / 256, 256, 0, stream>>>(ei, deg);
  k_scan1  <<<NB, 256, 0, stream>>>(deg, bsum);
  k_scan2  <<<1, 256, 0, stream>>>(bsum, boff);
  k_scan3  <<<NB, 256, 0, stream>>>(deg, boff, off, cursor);
  k_reorder<<<NEDGES / 256, 256, 0, stream>>>(ei, cursor, slot);
  if (use_h) {
    k_gather_h<<<(NNODES + 3) / 4, 256, 0, stream>>>(x, xh, off, slot, h);
  } else {
    k_gather_f<<<(NNODES + 3) / 4, 256, 0, stream>>>(x, off, slot, h);
  }
  k_gemm<0><<<(NNODES + 127) / 128, 256, 0, stream>>>(h, wp, b1, nullptr, stats, h);
  k_bnfin  <<<1, 128, 0, stream>>>(stats, gamma, beta, stats + 256);
  k_gemm<1><<<(NNODES + 127) / 128, 256, 0, stream>>>(h, wp + 32768, b2, stats + 256, nullptr, out);
}